// Round 13
// baseline (52222.107 us; speedup 1.0000x reference)
//
#include <hip/hip_runtime.h>
#include <cmath>

#define Hdim 768
#define Bb 32
#define Kb 5
#define Ss 64
#define Vv 30522
#define Tt 40
#define SEPTOK 102
#define NTLOG 477   // ceil(30522/64)

typedef __attribute__((ext_vector_type(2))) float f32x2;
typedef __attribute__((ext_vector_type(4))) float f32x4;

struct Params {
    const float *src, *E, *Wa, *Ua, *va, *W_ih, *W_hh, *b_ih, *b_hh, *Wo, *bo;
    float *srcWa, *hA, *hB, *hUa, *gxE, *gh;
    float *mt_g; double *st_g; float *t5v; int *t5j;
    float *scores, *ended, *lengths;
    int *toks_cur, *maps_cur, *toks_all, *maps_all, *outTok;
};

// ------------------------- top-k helpers -----------------------------------
__device__ __forceinline__ bool betterf(float va, int ja, float vb, int jb) {
    return (va > vb) || (va == vb && ja < jb);
}
__device__ __forceinline__ void ins5(float* tv, int* tj, float v, int j) {
    if (!betterf(v, j, tv[4], tj[4])) return;
    tv[4] = v; tj[4] = j;
#pragma unroll
    for (int q = 4; q > 0; q--) {
        if (betterf(tv[q], tj[q], tv[q - 1], tj[q - 1])) {
            float t = tv[q]; tv[q] = tv[q - 1]; tv[q - 1] = t;
            int  ti = tj[q]; tj[q] = tj[q - 1]; tj[q - 1] = ti;
        }
    }
}
__device__ __forceinline__ void ins5p(float* tv, int* tj, float* tx,
                                      float v, int j, float x) {
    if (!betterf(v, j, tv[4], tj[4])) return;
    tv[4] = v; tj[4] = j; tx[4] = x;
#pragma unroll
    for (int q = 4; q > 0; q--) {
        if (betterf(tv[q], tj[q], tv[q - 1], tj[q - 1])) {
            float t = tv[q]; tv[q] = tv[q - 1]; tv[q - 1] = t;
            int  ti = tj[q]; tj[q] = tj[q - 1]; tj[q - 1] = ti;
            float tz = tx[q]; tx[q] = tx[q - 1]; tx[q - 1] = tz;
        }
    }
}

// shared tile storage for GEMM-style kernels (~29.4 KB)
struct GS { float xs[32][162]; float wt[32][68]; };

// ---------------------------------------------------------------------------
// 160x64 one-shot-weight GEMM tile, 512 thr, micro-tile 10x2, K-chunk 32.
// xsrc: 0 = gathered h_old (zeros at t==0), 1 = emb tokens
// ---------------------------------------------------------------------------
__device__ void gemm512(GS& sm, const Params& P, int t, int N, int xsrc,
    int i0, int Pdim, const float* __restrict__ W, int ldW, bool pmaj,
    const float* __restrict__ bias, float* __restrict__ outp, int ldO, int Icap)
{
    const int tid = threadIdx.x;
    const int ty = tid >> 5, tx = tid & 31;
    const float* h_old = (t & 1) ? P.hB : P.hA;

    float acc[10][2];
#pragma unroll
    for (int j = 0; j < 10; j++) { acc[j][0] = 0.f; acc[j][1] = 0.f; }

    for (int c0 = 0; c0 < Pdim; c0 += 32) {
        __syncthreads();
        for (int e = tid; e < 160 * 32; e += 512) {
            int r = e >> 5, p = e & 31;
            int n = (r < N) ? r : (N - 1);
            float v = 0.f;
            if (xsrc == 0) {
                if (t != 0) {
                    int par = (n / Kb) * Kb + P.maps_cur[n];
                    v = h_old[(size_t)par * Hdim + c0 + p];
                }
            } else {
                int tok = (t == 0) ? SEPTOK : P.toks_cur[n];
                v = P.E[(size_t)tok * Hdim + c0 + p];
            }
            sm.xs[p][r] = v;
        }
        if (pmaj) {
            int p = tid >> 4, i4 = (tid & 15) * 4;
            int gi = i0 + i4;
            f32x4 a;
            if (gi + 3 < Icap) {
                a = *(const f32x4*)&W[(size_t)(c0 + p) * ldW + gi];
            } else {
#pragma unroll
                for (int u = 0; u < 4; u++) {
                    int g = gi + u; if (g >= Icap) g = Icap - 1;
                    a[u] = W[(size_t)(c0 + p) * ldW + g];
                }
            }
            *(f32x4*)&sm.wt[p][i4] = a;
        } else {
            int c = tid >> 3, p4 = (tid & 7) * 4;
            int gi = i0 + c; if (gi >= Icap) gi = Icap - 1;
            f32x4 a = *(const f32x4*)&W[(size_t)gi * ldW + c0 + p4];
            sm.wt[p4 + 0][c] = a[0]; sm.wt[p4 + 1][c] = a[1];
            sm.wt[p4 + 2][c] = a[2]; sm.wt[p4 + 3][c] = a[3];
        }
        __syncthreads();
        float part[10][2];
#pragma unroll
        for (int j = 0; j < 10; j++) { part[j][0] = 0.f; part[j][1] = 0.f; }
#pragma unroll
        for (int p = 0; p < 32; p++) {
            f32x2 w2 = *(const f32x2*)&sm.wt[p][tx * 2];
            float xr[10];
#pragma unroll
            for (int j = 0; j < 10; j += 2) {
                f32x2 xv = *(const f32x2*)&sm.xs[p][ty * 10 + j];
                xr[j] = xv.x; xr[j + 1] = xv.y;
            }
#pragma unroll
            for (int j = 0; j < 10; j++) {
                part[j][0] = fmaf(xr[j], w2.x, part[j][0]);
                part[j][1] = fmaf(xr[j], w2.y, part[j][1]);
            }
        }
#pragma unroll
        for (int j = 0; j < 10; j++) {
            acc[j][0] = __fadd_rn(acc[j][0], part[j][0]);
            acc[j][1] = __fadd_rn(acc[j][1], part[j][1]);
        }
    }
#pragma unroll
    for (int j = 0; j < 10; j++) {
        int r = ty * 10 + j;
        if (r < N) {
#pragma unroll
            for (int u = 0; u < 2; u++) {
                int gi = i0 + tx * 2 + u;
                if (gi < Icap) {
                    float v = acc[j][u];
                    if (bias) v = __fadd_rn(v, bias[gi]);
                    outp[(size_t)r * ldO + gi] = v;
                }
            }
        }
    }
}

// ---- P1 kernel: hUa (12 tiles) | gh (36) | gxE (36) ----
__global__ __launch_bounds__(512) void p1_k(Params P, int t, int N)
{
    __shared__ GS sm;
    int task = blockIdx.x;
    if (task < 12)
        gemm512(sm, P, t, N, 0, task * 64, Hdim, P.Ua, Hdim, true,
                nullptr, P.hUa, Hdim, Hdim);
    else if (task < 48)
        gemm512(sm, P, t, N, 0, (task - 12) * 64, Hdim, P.W_hh, Hdim, false,
                P.b_hh, P.gh, 2304, 2304);
    else
        gemm512(sm, P, t, N, 1, (task - 48) * 64, Hdim, P.W_ih, 1536, false,
                nullptr, P.gxE, 2304, 2304);
}

// ---- P2 kernel: per-row attn + ctx matvec + gate -> h2 ----
__global__ __launch_bounds__(512) void p2_k(Params P, int t, int N)
{
    __shared__ float hu[Hdim];
    __shared__ float va_s[Hdim];
    __shared__ float e_s[Ss];
    __shared__ float a_s[Ss];
    __shared__ float ctx[Hdim];
    __shared__ float gx[2304];
    const int tid = threadIdx.x;
    const int n = blockIdx.x;
    if (n >= N) return;
    const int Kcur = (t == 0) ? 1 : Kb;
    const int b = n / Kcur;
    float* h_new = (t & 1) ? P.hA : P.hB;
    const float* h_old = (t & 1) ? P.hB : P.hA;

    for (int j = tid; j < Hdim; j += 512) {
        hu[j]   = P.hUa[(size_t)n * Hdim + j];
        va_s[j] = P.va[j];
    }
    __syncthreads();
    {
        int wv = tid >> 6, ln = tid & 63;
        for (int s = wv * 8; s < wv * 8 + 8; s++) {
            const float* sw = P.srcWa + (size_t)(b * Ss + s) * Hdim;
            double p = 0.0;
            for (int j = ln; j < Hdim; j += 64) {
                float tv = tanhf(__fadd_rn(sw[j], hu[j]));
                p = ::fma((double)tv, (double)va_s[j], p);
            }
            for (int off = 32; off; off >>= 1) p += __shfl_down(p, off, 64);
            if (ln == 0) e_s[s] = (float)p;
        }
    }
    __syncthreads();
    if (tid < 64) {
        float v = e_s[tid], m = v;
        for (int off = 32; off; off >>= 1) m = fmaxf(m, __shfl_xor(m, off, 64));
        float p = expf(__fsub_rn(v, m));
        double sum = (double)p;
        for (int off = 32; off; off >>= 1) sum += __shfl_xor(sum, off, 64);
        a_s[tid] = __fdiv_rn(p, (float)sum);
    }
    __syncthreads();
    for (int j = tid; j < Hdim; j += 512) {
        double acc = 0.0;
        for (int s = 0; s < Ss; s++)
            acc = ::fma((double)a_s[s],
                        (double)P.src[(size_t)(b * Ss + s) * Hdim + j], acc);
        ctx[j] = (float)acc;
    }
    __syncthreads();
    for (int i = tid; i < 2304; i += 512) {
        const float* wr = P.W_ih + (size_t)i * 1536 + 768;
        float accv = 0.f, part = 0.f;
        for (int p = 0; p < 768; p += 4) {
            f32x4 w4 = *(const f32x4*)&wr[p];
            part = fmaf(ctx[p + 0], w4[0], part);
            part = fmaf(ctx[p + 1], w4[1], part);
            part = fmaf(ctx[p + 2], w4[2], part);
            part = fmaf(ctx[p + 3], w4[3], part);
            if ((p & 31) == 28) { accv = __fadd_rn(accv, part); part = 0.f; }
        }
        gx[i] = __fadd_rn(__fadd_rn(P.gxE[(size_t)n * 2304 + i], accv), P.b_ih[i]);
    }
    __syncthreads();
    int par = 0;
    if (t != 0) par = (n / Kb) * Kb + P.maps_cur[n];
    for (int i = tid; i < Hdim; i += 512) {
        float xr = gx[i], xz = gx[768 + i], xn = gx[1536 + i];
        const float* ghr = P.gh + (size_t)n * 2304;
        float hr = ghr[i], hz = ghr[768 + i], hn = ghr[1536 + i];
        float r  = __fdiv_rn(1.f, __fadd_rn(1.f, expf(-__fadd_rn(xr, hr))));
        float z  = __fdiv_rn(1.f, __fadd_rn(1.f, expf(-__fadd_rn(xz, hz))));
        float nn = tanhf(__fadd_rn(xn, __fmul_rn(r, hn)));
        float hv = (t == 0) ? 0.f : h_old[(size_t)par * Hdim + i];
        float h2 = __fadd_rn(__fmul_rn(__fsub_rn(1.f, z), nn), __fmul_rn(z, hv));
        if (t == 0) {
            for (int k = 0; k < Kb; k++)
                h_new[(size_t)(n * Kb + k) * Hdim + i] = h2;
        } else {
            h_new[(size_t)n * Hdim + i] = h2;
        }
    }
}

// ---- P4 kernel: logits tile -> (max, sum expf, top-5 raw) partials ----
__global__ __launch_bounds__(512) void p4_k(Params P, int t, int N)
{
    __shared__ GS sm;
    const int tid = threadIdx.x;
    const int ty = tid >> 5, tx = tid & 31;
    const int task = blockIdx.x;
    const int i0 = task * 64;
    const float* h_new = (t & 1) ? P.hA : P.hB;
    const int rowMul = (t == 0) ? Kb : 1;

    float acc[10][2];
#pragma unroll
    for (int j = 0; j < 10; j++) { acc[j][0] = 0.f; acc[j][1] = 0.f; }

    for (int c0 = 0; c0 < Hdim; c0 += 32) {
        __syncthreads();
        for (int e = tid; e < 160 * 32; e += 512) {
            int r = e >> 5, p = e & 31;
            int n = (r < N) ? r : (N - 1);
            sm.xs[p][r] = h_new[((size_t)n * rowMul) * Hdim + c0 + p];
        }
        {
            int c = tid >> 3, p4 = (tid & 7) * 4;
            int gi = i0 + c; if (gi >= Vv) gi = Vv - 1;
            f32x4 a = *(const f32x4*)&P.Wo[(size_t)gi * Hdim + c0 + p4];
            sm.wt[p4 + 0][c] = a[0]; sm.wt[p4 + 1][c] = a[1];
            sm.wt[p4 + 2][c] = a[2]; sm.wt[p4 + 3][c] = a[3];
        }
        __syncthreads();
        float part[10][2];
#pragma unroll
        for (int j = 0; j < 10; j++) { part[j][0] = 0.f; part[j][1] = 0.f; }
#pragma unroll
        for (int p = 0; p < 32; p++) {
            f32x2 w2 = *(const f32x2*)&sm.wt[p][tx * 2];
            float xr[10];
#pragma unroll
            for (int j = 0; j < 10; j += 2) {
                f32x2 xv = *(const f32x2*)&sm.xs[p][ty * 10 + j];
                xr[j] = xv.x; xr[j + 1] = xv.y;
            }
#pragma unroll
            for (int j = 0; j < 10; j++) {
                part[j][0] = fmaf(xr[j], w2.x, part[j][0]);
                part[j][1] = fmaf(xr[j], w2.y, part[j][1]);
            }
        }
#pragma unroll
        for (int j = 0; j < 10; j++) {
            acc[j][0] = __fadd_rn(acc[j][0], part[j][0]);
            acc[j][1] = __fadd_rn(acc[j][1], part[j][1]);
        }
    }
    // epilogue: per-row max / sumexp / top5 in registers (32-lane groups)
#pragma unroll
    for (int j = 0; j < 10; j++) {
        int r = ty * 10 + j;
        int g0 = i0 + tx * 2, g1 = g0 + 1;
        float x0 = (g0 < Vv) ? __fadd_rn(acc[j][0], P.bo[g0]) : -INFINITY;
        float x1 = (g1 < Vv) ? __fadd_rn(acc[j][1], P.bo[g1]) : -INFINITY;
        float mr = fmaxf(x0, x1);
#pragma unroll
        for (int off = 16; off; off >>= 1)
            mr = fmaxf(mr, __shfl_xor(mr, off, 32));
        double s = (double)expf(__fsub_rn(x0, mr)) + (double)expf(__fsub_rn(x1, mr));
#pragma unroll
        for (int off = 16; off; off >>= 1)
            s += __shfl_xor(s, off, 32);
        float tv[5]; int tj[5];
#pragma unroll
        for (int q = 0; q < 5; q++) { tv[q] = -INFINITY; tj[q] = 0x7fffffff; }
        ins5(tv, tj, x0, (g0 < Vv) ? g0 : 0x7fffffff);
        ins5(tv, tj, x1, (g1 < Vv) ? g1 : 0x7fffffff);
#pragma unroll
        for (int lv = 1; lv < 32; lv <<= 1) {
            float pv[5]; int pj[5];
#pragma unroll
            for (int q = 0; q < 5; q++) {
                pv[q] = __shfl_xor(tv[q], lv, 32);
                pj[q] = __shfl_xor(tj[q], lv, 32);
            }
#pragma unroll
            for (int q = 0; q < 5; q++) ins5(tv, tj, pv[q], pj[q]);
        }
        if (tx == 0 && r < N) {
            P.mt_g[(size_t)task * 160 + r] = mr;
            P.st_g[(size_t)task * 160 + r] = s;
#pragma unroll
            for (int q = 0; q < 5; q++) {
                P.t5v[((size_t)task * 160 + r) * 5 + q] = tv[q];
                P.t5j[((size_t)task * 160 + r) * 5 + q] = tj[q];
            }
        }
    }
}

// ---- P5 kernel: per-batch merge + select ----
__global__ __launch_bounds__(512) void p5_k(Params P, int t)
{
    __shared__ float sc[Kb], den[Kb], endd[Kb], len[Kb], mxs[Kb], lgv[Kb];
    __shared__ float mv[256 * 5]; __shared__ int mj[256 * 5];
    __shared__ float mxp[256 * 5];
    __shared__ float rv[512]; __shared__ int rj[512]; __shared__ float rx[512];
    __shared__ double rd[512];
    __shared__ int selj[Kb]; __shared__ float selx[Kb];
    const int tid = threadIdx.x;
    const int b = blockIdx.x;
    const int Kcur = (t == 0) ? 1 : Kb;

    if (tid < Kb) {
        if (t == 0) {
            sc[tid] = 0.f; endd[tid] = 0.f; len[tid] = 0.f; den[tid] = 1.f;
        } else {
            float e0 = P.ended[b * Kb + tid];
            float ln = __fadd_rn(P.lengths[b * Kb + tid], (e0 == 0.f) ? 1.f : 0.f);
            sc[tid]  = P.scores[b * Kb + tid];
            endd[tid] = e0;
            len[tid] = ln;
            den[tid] = (tid < Kb - 1) ? (float)pow((double)ln, (double)0.7f) : 1.f;
        }
    }
    __syncthreads();
    for (int k = 0; k < Kcur; k++) {
        bool active = (t == 0) || (endd[k] == 0.f);
        if (!active) {
            if (tid == 0) { mxs[k] = 0.f; lgv[k] = 0.f; }
            __syncthreads();
            continue;
        }
        int n = b * Kcur + k;
        float m = -INFINITY;
        for (int tile = tid; tile < NTLOG; tile += 512)
            m = fmaxf(m, P.mt_g[(size_t)tile * 160 + n]);
        rv[tid] = m; __syncthreads();
        for (int off = 256; off; off >>= 1) {
            if (tid < off) rv[tid] = fmaxf(rv[tid], rv[tid + off]);
            __syncthreads();
        }
        m = rv[0];
        double s = 0.0;
        for (int tile = tid; tile < NTLOG; tile += 512)
            s += P.st_g[(size_t)tile * 160 + n] *
                 exp((double)(P.mt_g[(size_t)tile * 160 + n] - m));
        __syncthreads();
        rd[tid] = s; __syncthreads();
        for (int off = 256; off; off >>= 1) {
            if (tid < off) rd[tid] += rd[tid + off];
            __syncthreads();
        }
        if (tid == 0) {
            mxs[k] = m;
            float sf = (float)rd[0];
            lgv[k] = (float)log((double)sf);
        }
        __syncthreads();
    }
    // candidate merge: Kcur x 477 x 5 entries
    float tv[5]; int tj[5]; float txx[5];
#pragma unroll
    for (int q = 0; q < 5; q++) { tv[q] = -INFINITY; tj[q] = 0x7fffffff; txx[q] = 0.f; }
    if (tid < 256) {
        int tot = Kcur * NTLOG * 5;
        for (int c = tid; c < tot; c += 256) {
            int k = c / (NTLOG * 5);
            if (t != 0 && endd[k] != 0.f) continue;
            int rm = c - k * NTLOG * 5;
            int tile = rm / 5, q = rm - tile * 5;
            int n = b * Kcur + k;
            int gi = P.t5j[((size_t)tile * 160 + n) * 5 + q];
            if (gi == 0x7fffffff) continue;
            float x = P.t5v[((size_t)tile * 160 + n) * 5 + q];
            float lp  = __fsub_rn(__fsub_rn(x, mxs[k]), lgv[k]);
            float val = __fdiv_rn(__fadd_rn(lp, sc[k]), den[k]);
            ins5p(tv, tj, txx, val, k * Vv + gi, x);
        }
    }
    if (tid == 0 && t != 0) {
        for (int k = 0; k < Kcur; k++)
            if (endd[k] != 0.f) {
                float val = __fdiv_rn(sc[k], den[k]);
                ins5p(tv, tj, txx, val, k * Vv + SEPTOK, 0.f);
            }
    }
    if (tid < 256) {
#pragma unroll
        for (int q = 0; q < 5; q++) {
            mv[tid * 5 + q] = tv[q];
            mj[tid * 5 + q] = tj[q];
            mxp[tid * 5 + q] = txx[q];
        }
    }
    __syncthreads();
    for (int pass = 0; pass < Kb; pass++) {
        if (tid < 256) {
            float bv = -INFINITY; int bj = 0x7fffffff; float bx = 0.f;
#pragma unroll
            for (int q = 0; q < 5; q++) {
                float v = mv[tid * 5 + q]; int j = mj[tid * 5 + q];
                if (betterf(v, j, bv, bj)) { bv = v; bj = j; bx = mxp[tid * 5 + q]; }
            }
            rv[tid] = bv; rj[tid] = bj; rx[tid] = bx;
        }
        __syncthreads();
        for (int off = 128; off; off >>= 1) {
            if (tid < off) {
                float ov = rv[tid + off]; int oj = rj[tid + off];
                if (betterf(ov, oj, rv[tid], rj[tid])) {
                    rv[tid] = ov; rj[tid] = oj; rx[tid] = rx[tid + off];
                }
            }
            __syncthreads();
        }
        if (tid == 0) { selj[pass] = rj[0]; selx[pass] = rx[0]; }
        __syncthreads();
        if (tid < 256) {
#pragma unroll
            for (int q = 0; q < 5; q++)
                if (mj[tid * 5 + q] == selj[pass]) {
                    mv[tid * 5 + q] = -INFINITY;
                    mj[tid * 5 + q] = 0x7fffffff;
                }
        }
        __syncthreads();
    }
    if (tid == 0) {
        for (int q = 0; q < Kb; q++) {
            int jj = selj[q];
            int pk = jj / Vv, vv = jj - pk * Vv;
            float lp;
            if (t == 0 || endd[pk] == 0.f)
                lp = __fsub_rn(__fsub_rn(selx[q], mxs[pk]), lgv[pk]);
            else
                lp = (vv == SEPTOK) ? 0.f : -1e9f;
            float cand = __fadd_rn(lp, sc[pk]);
            P.scores[b * Kb + q]   = cand;
            P.toks_cur[b * Kb + q] = vv;
            P.maps_cur[b * Kb + q] = (t == 0) ? 0 : pk;
            if (t == 0) {
                P.ended[b * Kb + q]   = 0.f;
                P.lengths[b * Kb + q] = 0.f;
            } else {
                P.ended[b * Kb + q]   = (vv == SEPTOK) ? 1.f : endd[q];
                P.lengths[b * Kb + q] = len[q];
            }
            P.toks_all[(size_t)t * Bb * Kb + b * Kb + q] = vv;
            P.maps_all[(size_t)t * Bb * Kb + b * Kb + q] = (t == 0) ? 0 : pk;
        }
    }
}

__global__ void back_k(Params P)
{
    int b = threadIdx.x;
    if (b >= Bb) return;
    int best = 0; float bvv = P.scores[b * Kb];
    for (int k = 1; k < Kb; k++) {
        float v = P.scores[b * Kb + k];
        if (v > bvv) { bvv = v; best = k; }
    }
    int cur = best;
    for (int t = Tt - 1; t >= 0; t--) {
        P.outTok[b * Tt + t] = P.toks_all[t * Bb * Kb + b * Kb + cur];
        cur = P.maps_all[t * Bb * Kb + b * Kb + cur];
    }
}

// ---- one-time srcWa GEMM (r10-proven) ----
template<int RPT, int CPT, bool PMAJ>
__global__ __launch_bounds__(512) void gemmN_k(int P, int I, int xrs, int ldW,
    const float* __restrict__ X, const float* __restrict__ W,
    const float* __restrict__ bias, float* __restrict__ out, int ldO)
{
    constexpr int ROWS = RPT * 16;
    constexpr int COLS = CPT * 32;
    constexpr int XST  = ROWS + 4;
    constexpr int WST  = COLS + 4;
    __shared__ float xs[32][XST];
    __shared__ float wt[32][WST];
    const int tid = threadIdx.x;
    const int ty = tid >> 5, tx = tid & 31;
    const int row0 = blockIdx.y * ROWS;
    const int i0 = blockIdx.x * COLS;

    float acc[RPT][CPT];
#pragma unroll
    for (int j = 0; j < RPT; j++)
#pragma unroll
        for (int u = 0; u < CPT; u++) acc[j][u] = 0.f;

    for (int c0 = 0; c0 < P; c0 += 32) {
        __syncthreads();
        for (int e = tid; e < ROWS * 32; e += 512) {
            int r = e >> 5, p = e & 31;
            xs[p][r] = X[(size_t)(row0 + r) * xrs + c0 + p];
        }
        if (PMAJ) {
            for (int v = tid; v < 32 * (COLS / 4); v += 512) {
                int p  = v / (COLS / 4);
                int i4 = (v % (COLS / 4)) * 4;
                f32x4 a;
                if (i0 + i4 + 3 < I) {
                    a = *(const f32x4*)&W[(size_t)(c0 + p) * ldW + i0 + i4];
                } else {
#pragma unroll
                    for (int u = 0; u < 4; u++) {
                        int g = i0 + i4 + u; if (g >= I) g = I - 1;
                        a[u] = W[(size_t)(c0 + p) * ldW + g];
                    }
                }
                *(f32x4*)&wt[p][i4] = a;
            }
        } else {
            for (int v = tid; v < COLS * 8; v += 512) {
                int c  = v >> 3;
                int p4 = (v & 7) * 4;
                int gi = i0 + c; if (gi >= I) gi = I - 1;
                f32x4 a = *(const f32x4*)&W[(size_t)gi * ldW + c0 + p4];
                wt[p4 + 0][c] = a[0]; wt[p4 + 1][c] = a[1];
                wt[p4 + 2][c] = a[2]; wt[p4 + 3][c] = a[3];
            }
        }
        __syncthreads();
        float part[RPT][CPT];
#pragma unroll
        for (int j = 0; j < RPT; j++)
#pragma unroll
            for (int u = 0; u < CPT; u++) part[j][u] = 0.f;
#pragma unroll
        for (int p = 0; p < 32; p++) {
            float xr[RPT];
#pragma unroll
            for (int j = 0; j < RPT; j += 2) {
                f32x2 xv = *(const f32x2*)&xs[p][ty * RPT + j];
                xr[j] = xv.x; xr[j + 1] = xv.y;
            }
            float wv[CPT];
#pragma unroll
            for (int u = 0; u < CPT; u += 2) {
                f32x2 w2 = *(const f32x2*)&wt[p][tx * CPT + u];
                wv[u] = w2.x; wv[u + 1] = w2.y;
            }
#pragma unroll
            for (int j = 0; j < RPT; j++)
#pragma unroll
                for (int u = 0; u < CPT; u++)
                    part[j][u] = fmaf(xr[j], wv[u], part[j][u]);
        }
#pragma unroll
        for (int j = 0; j < RPT; j++)
#pragma unroll
            for (int u = 0; u < CPT; u++)
                acc[j][u] = __fadd_rn(acc[j][u], part[j][u]);
    }
#pragma unroll
    for (int j = 0; j < RPT; j++) {
        int gr = row0 + ty * RPT + j;
#pragma unroll
        for (int u = 0; u < CPT; u++) {
            int gi = i0 + tx * CPT + u;
            if (gi < I) {
                float v = acc[j][u];
                if (bias) v = __fadd_rn(v, bias[gi]);
                out[(size_t)gr * ldO + gi] = v;
            }
        }
    }
}

// ---------------------------------------------------------------------------
extern "C" void kernel_launch(void* const* d_in, const int* in_sizes, int n_in,
                              void* d_out, int out_size, void* d_ws, size_t ws_size,
                              hipStream_t stream)
{
    Params P;
    P.src  = (const float*)d_in[0];
    P.E    = (const float*)d_in[1];
    P.Wa   = (const float*)d_in[2];
    P.Ua   = (const float*)d_in[3];
    P.va   = (const float*)d_in[4];
    P.W_ih = (const float*)d_in[5];
    P.W_hh = (const float*)d_in[6];
    P.b_ih = (const float*)d_in[7];
    P.b_hh = (const float*)d_in[8];
    P.Wo   = (const float*)d_in[9];
    P.bo   = (const float*)d_in[10];
    P.outTok = (int*)d_out;

    char* w = (char*)d_ws;
    size_t used = 0;
    auto alloc = [&](size_t bytes) -> char* {
        char* p = w + used;
        used += (bytes + 255) & ~(size_t)255;
        return p;
    };
    P.srcWa   = (float*)alloc((size_t)Bb * Ss * Hdim * 4);
    P.hA      = (float*)alloc((size_t)Bb * Kb * Hdim * 4);
    P.hB      = (float*)alloc((size_t)Bb * Kb * Hdim * 4);
    P.hUa     = (float*)alloc((size_t)Bb * Kb * Hdim * 4);
    P.gxE     = (float*)alloc((size_t)Bb * Kb * 2304 * 4);
    P.gh      = (float*)alloc((size_t)Bb * Kb * 2304 * 4);
    P.mt_g    = (float*)alloc((size_t)NTLOG * 160 * 4);
    P.st_g    = (double*)alloc((size_t)NTLOG * 160 * 8);
    P.t5v     = (float*)alloc((size_t)NTLOG * 160 * 5 * 4);
    P.t5j     = (int*)alloc((size_t)NTLOG * 160 * 5 * 4);
    P.scores  = (float*)alloc(Bb * Kb * 4);
    P.ended   = (float*)alloc(Bb * Kb * 4);
    P.lengths = (float*)alloc(Bb * Kb * 4);
    P.toks_cur = (int*)alloc(Bb * Kb * 4);
    P.maps_cur = (int*)alloc(Bb * Kb * 4);
    P.toks_all = (int*)alloc((size_t)Tt * Bb * Kb * 4);
    P.maps_all = (int*)alloc((size_t)Tt * Bb * Kb * 4);

    // one-time srcWa = src @ Wa
    gemmN_k<8, 2, true><<<dim3(12, 16), 512, 0, stream>>>(
        Hdim, Hdim, Hdim, Hdim, P.src, P.Wa, nullptr, P.srcWa, Hdim);

    for (int t = 0; t < Tt; t++) {
        int N = (t == 0) ? Bb : Bb * Kb;
        p1_k<<<84, 512, 0, stream>>>(P, t, N);
        p2_k<<<N, 512, 0, stream>>>(P, t, N);
        p4_k<<<NTLOG, 512, 0, stream>>>(P, t, N);
        p5_k<<<Bb, 512, 0, stream>>>(P, t);
    }
    back_k<<<1, 64, 0, stream>>>(P);
}

// Round 14
// 45912.488 us; speedup vs baseline: 1.1374x; 1.1374x over previous
//
#include <hip/hip_runtime.h>
#include <cmath>

#define Hdim 768
#define Bb 32
#define Kb 5
#define Ss 64
#define Vv 30522
#define Tt 40
#define SEPTOK 102
#define NTLOG 477   // ceil(30522/64)

typedef __attribute__((ext_vector_type(2))) float f32x2;
typedef __attribute__((ext_vector_type(4))) float f32x4;

struct Params {
    const float *src, *E, *Wa, *Ua, *va, *W_ih, *W_hh, *b_ih, *b_hh, *Wo, *bo;
    float *srcWa, *hA, *hB, *hUa, *gxE, *gx, *gh, *ctx;
    float *mt_g; double *st_g; float *t5v; int *t5j;
    float *scores, *ended, *lengths;
    int *toks_cur, *maps_cur, *toks_all, *maps_all, *outTok;
};

// ------------------------- top-k helpers -----------------------------------
__device__ __forceinline__ bool betterf(float va, int ja, float vb, int jb) {
    return (va > vb) || (va == vb && ja < jb);
}
__device__ __forceinline__ void ins5(float* tv, int* tj, float v, int j) {
    if (!betterf(v, j, tv[4], tj[4])) return;
    tv[4] = v; tj[4] = j;
#pragma unroll
    for (int q = 4; q > 0; q--) {
        if (betterf(tv[q], tj[q], tv[q - 1], tj[q - 1])) {
            float t = tv[q]; tv[q] = tv[q - 1]; tv[q - 1] = t;
            int  ti = tj[q]; tj[q] = tj[q - 1]; tj[q - 1] = ti;
        }
    }
}
__device__ __forceinline__ void ins5p(float* tv, int* tj, float* tx,
                                      float v, int j, float x) {
    if (!betterf(v, j, tv[4], tj[4])) return;
    tv[4] = v; tj[4] = j; tx[4] = x;
#pragma unroll
    for (int q = 4; q > 0; q--) {
        if (betterf(tv[q], tj[q], tv[q - 1], tj[q - 1])) {
            float t = tv[q]; tv[q] = tv[q - 1]; tv[q - 1] = t;
            int  ti = tj[q]; tj[q] = tj[q - 1]; tj[q - 1] = ti;
            float tz = tx[q]; tx[q] = tx[q - 1]; tx[q - 1] = tz;
        }
    }
}

// shared tile storage for GEMM-style kernels (~28.8 KB)
struct GS { float xs[32][162]; float wt[32][68]; };

// ---------------------------------------------------------------------------
// 160x64 one-shot-weight GEMM tile, 512 thr, micro-tile 10x2, K-chunk 32.
// xsrc: 0 = gathered h_old (zeros at t==0), 1 = emb tokens, 2 = ctx
// addm: optional per-element pre-add (gx = addm + acc, then +bias)
// ---------------------------------------------------------------------------
__device__ void gemm512(GS& sm, const Params& P, int t, int N, int xsrc,
    int i0, int Pdim, const float* __restrict__ W, int ldW, bool pmaj,
    const float* __restrict__ bias, const float* __restrict__ addm, int ldA,
    float* __restrict__ outp, int ldO, int Icap)
{
    const int tid = threadIdx.x;
    const int ty = tid >> 5, tx = tid & 31;
    const float* h_old = (t & 1) ? P.hB : P.hA;

    float acc[10][2];
#pragma unroll
    for (int j = 0; j < 10; j++) { acc[j][0] = 0.f; acc[j][1] = 0.f; }

    for (int c0 = 0; c0 < Pdim; c0 += 32) {
        __syncthreads();
        for (int e = tid; e < 160 * 32; e += 512) {
            int r = e >> 5, p = e & 31;
            int n = (r < N) ? r : (N - 1);
            float v = 0.f;
            if (xsrc == 0) {
                if (t != 0) {
                    int par = (n / Kb) * Kb + P.maps_cur[n];
                    v = h_old[(size_t)par * Hdim + c0 + p];
                }
            } else if (xsrc == 1) {
                int tok = (t == 0) ? SEPTOK : P.toks_cur[n];
                v = P.E[(size_t)tok * Hdim + c0 + p];
            } else {
                v = P.ctx[(size_t)n * Hdim + c0 + p];
            }
            sm.xs[p][r] = v;
        }
        if (pmaj) {
            int p = tid >> 4, i4 = (tid & 15) * 4;
            int gi = i0 + i4;
            f32x4 a;
            if (gi + 3 < Icap) {
                a = *(const f32x4*)&W[(size_t)(c0 + p) * ldW + gi];
            } else {
#pragma unroll
                for (int u = 0; u < 4; u++) {
                    int g = gi + u; if (g >= Icap) g = Icap - 1;
                    a[u] = W[(size_t)(c0 + p) * ldW + g];
                }
            }
            *(f32x4*)&sm.wt[p][i4] = a;
        } else {
            int c = tid >> 3, p4 = (tid & 7) * 4;
            int gi = i0 + c; if (gi >= Icap) gi = Icap - 1;
            f32x4 a = *(const f32x4*)&W[(size_t)gi * ldW + c0 + p4];
            sm.wt[p4 + 0][c] = a[0]; sm.wt[p4 + 1][c] = a[1];
            sm.wt[p4 + 2][c] = a[2]; sm.wt[p4 + 3][c] = a[3];
        }
        __syncthreads();
        float part[10][2];
#pragma unroll
        for (int j = 0; j < 10; j++) { part[j][0] = 0.f; part[j][1] = 0.f; }
#pragma unroll
        for (int p = 0; p < 32; p++) {
            f32x2 w2 = *(const f32x2*)&sm.wt[p][tx * 2];
            float xr[10];
#pragma unroll
            for (int j = 0; j < 10; j += 2) {
                f32x2 xv = *(const f32x2*)&sm.xs[p][ty * 10 + j];
                xr[j] = xv.x; xr[j + 1] = xv.y;
            }
#pragma unroll
            for (int j = 0; j < 10; j++) {
                part[j][0] = fmaf(xr[j], w2.x, part[j][0]);
                part[j][1] = fmaf(xr[j], w2.y, part[j][1]);
            }
        }
#pragma unroll
        for (int j = 0; j < 10; j++) {
            acc[j][0] = __fadd_rn(acc[j][0], part[j][0]);
            acc[j][1] = __fadd_rn(acc[j][1], part[j][1]);
        }
    }
#pragma unroll
    for (int j = 0; j < 10; j++) {
        int r = ty * 10 + j;
        if (r < N) {
#pragma unroll
            for (int u = 0; u < 2; u++) {
                int gi = i0 + tx * 2 + u;
                if (gi < Icap) {
                    float v = acc[j][u];
                    if (addm) v = __fadd_rn(addm[(size_t)r * ldA + gi], v);
                    if (bias) v = __fadd_rn(v, bias[gi]);
                    outp[(size_t)r * ldO + gi] = v;
                }
            }
        }
    }
}

// ---- P1 kernel: hUa (12 tiles) | gh (36) | gxE (36) ----
__global__ __launch_bounds__(512) void p1_k(Params P, int t, int N)
{
    __shared__ GS sm;
    int task = blockIdx.x;
    if (task < 12)
        gemm512(sm, P, t, N, 0, task * 64, Hdim, P.Ua, Hdim, true,
                nullptr, nullptr, 0, P.hUa, Hdim, Hdim);
    else if (task < 48)
        gemm512(sm, P, t, N, 0, (task - 12) * 64, Hdim, P.W_hh, Hdim, false,
                P.b_hh, nullptr, 0, P.gh, 2304, 2304);
    else
        gemm512(sm, P, t, N, 1, (task - 48) * 64, Hdim, P.W_ih, 1536, false,
                nullptr, nullptr, 0, P.gxE, 2304, 2304);
}

// ---- P2a kernel: per-row attention -> ctx ----
__global__ __launch_bounds__(512) void p2a_k(Params P, int t, int N)
{
    __shared__ float hu[Hdim];
    __shared__ float va_s[Hdim];
    __shared__ float e_s[Ss];
    __shared__ float a_s[Ss];
    const int tid = threadIdx.x;
    const int n = blockIdx.x;
    if (n >= N) return;
    const int Kcur = (t == 0) ? 1 : Kb;
    const int b = n / Kcur;

    for (int j = tid; j < Hdim; j += 512) {
        hu[j]   = P.hUa[(size_t)n * Hdim + j];
        va_s[j] = P.va[j];
    }
    __syncthreads();
    {
        int wv = tid >> 6, ln = tid & 63;
        for (int s = wv * 8; s < wv * 8 + 8; s++) {
            const float* sw = P.srcWa + (size_t)(b * Ss + s) * Hdim;
            double p = 0.0;
            for (int j = ln; j < Hdim; j += 64) {
                float tv = tanhf(__fadd_rn(sw[j], hu[j]));
                p = ::fma((double)tv, (double)va_s[j], p);
            }
            for (int off = 32; off; off >>= 1) p += __shfl_down(p, off, 64);
            if (ln == 0) e_s[s] = (float)p;
        }
    }
    __syncthreads();
    if (tid < 64) {
        float v = e_s[tid], m = v;
        for (int off = 32; off; off >>= 1) m = fmaxf(m, __shfl_xor(m, off, 64));
        float p = expf(__fsub_rn(v, m));
        double sum = (double)p;
        for (int off = 32; off; off >>= 1) sum += __shfl_xor(sum, off, 64);
        a_s[tid] = __fdiv_rn(p, (float)sum);
    }
    __syncthreads();
    for (int j = tid; j < Hdim; j += 512) {
        double acc = 0.0;
        for (int s = 0; s < Ss; s++)
            acc = ::fma((double)a_s[s],
                        (double)P.src[(size_t)(b * Ss + s) * Hdim + j], acc);
        P.ctx[(size_t)n * Hdim + j] = (float)acc;
    }
}

// ---- P2b kernel: gx = gxE + ctx @ W_ih(right)^T + b_ih  (36 tiles) ----
__global__ __launch_bounds__(512) void p2b_k(Params P, int t, int N)
{
    __shared__ GS sm;
    gemm512(sm, P, t, N, 2, blockIdx.x * 64, Hdim, P.W_ih + 768, 1536, false,
            P.b_ih, P.gxE, 2304, P.gx, 2304, 2304);
}

// ---- P2c kernel: elementwise GRU gate -> h_new (t0: broadcast 5 slots) ----
__global__ __launch_bounds__(512) void p2c_k(Params P, int t, int N)
{
    int idx = blockIdx.x * 512 + threadIdx.x;
    if (idx >= N * Hdim) return;
    int n = idx / Hdim, i = idx - n * Hdim;
    float* h_new = (t & 1) ? P.hA : P.hB;
    const float* h_old = (t & 1) ? P.hB : P.hA;
    const float* gxr = P.gx + (size_t)n * 2304;
    const float* ghr = P.gh + (size_t)n * 2304;
    float xr = gxr[i], xz = gxr[768 + i], xn = gxr[1536 + i];
    float hr = ghr[i], hz = ghr[768 + i], hn = ghr[1536 + i];
    float r  = __fdiv_rn(1.f, __fadd_rn(1.f, expf(-__fadd_rn(xr, hr))));
    float z  = __fdiv_rn(1.f, __fadd_rn(1.f, expf(-__fadd_rn(xz, hz))));
    float nn = tanhf(__fadd_rn(xn, __fmul_rn(r, hn)));
    float hv = 0.f;
    if (t != 0) {
        int par = (n / Kb) * Kb + P.maps_cur[n];
        hv = h_old[(size_t)par * Hdim + i];
    }
    float h2 = __fadd_rn(__fmul_rn(__fsub_rn(1.f, z), nn), __fmul_rn(z, hv));
    if (t == 0) {
        for (int k = 0; k < Kb; k++)
            h_new[(size_t)(n * Kb + k) * Hdim + i] = h2;
    } else {
        h_new[(size_t)n * Hdim + i] = h2;
    }
}

// ---- P4 kernel: logits tile -> (max, sum expf, top-5 raw) partials ----
__global__ __launch_bounds__(512) void p4_k(Params P, int t, int N)
{
    __shared__ GS sm;
    const int tid = threadIdx.x;
    const int ty = tid >> 5, tx = tid & 31;
    const int task = blockIdx.x;
    const int i0 = task * 64;
    const float* h_new = (t & 1) ? P.hA : P.hB;
    const int rowMul = (t == 0) ? Kb : 1;

    float acc[10][2];
#pragma unroll
    for (int j = 0; j < 10; j++) { acc[j][0] = 0.f; acc[j][1] = 0.f; }

    for (int c0 = 0; c0 < Hdim; c0 += 32) {
        __syncthreads();
        for (int e = tid; e < 160 * 32; e += 512) {
            int r = e >> 5, p = e & 31;
            int n = (r < N) ? r : (N - 1);
            sm.xs[p][r] = h_new[((size_t)n * rowMul) * Hdim + c0 + p];
        }
        {
            int c = tid >> 3, p4 = (tid & 7) * 4;
            int gi = i0 + c; if (gi >= Vv) gi = Vv - 1;
            f32x4 a = *(const f32x4*)&P.Wo[(size_t)gi * Hdim + c0 + p4];
            sm.wt[p4 + 0][c] = a[0]; sm.wt[p4 + 1][c] = a[1];
            sm.wt[p4 + 2][c] = a[2]; sm.wt[p4 + 3][c] = a[3];
        }
        __syncthreads();
        float part[10][2];
#pragma unroll
        for (int j = 0; j < 10; j++) { part[j][0] = 0.f; part[j][1] = 0.f; }
#pragma unroll
        for (int p = 0; p < 32; p++) {
            f32x2 w2 = *(const f32x2*)&sm.wt[p][tx * 2];
            float xr[10];
#pragma unroll
            for (int j = 0; j < 10; j += 2) {
                f32x2 xv = *(const f32x2*)&sm.xs[p][ty * 10 + j];
                xr[j] = xv.x; xr[j + 1] = xv.y;
            }
#pragma unroll
            for (int j = 0; j < 10; j++) {
                part[j][0] = fmaf(xr[j], w2.x, part[j][0]);
                part[j][1] = fmaf(xr[j], w2.y, part[j][1]);
            }
        }
#pragma unroll
        for (int j = 0; j < 10; j++) {
            acc[j][0] = __fadd_rn(acc[j][0], part[j][0]);
            acc[j][1] = __fadd_rn(acc[j][1], part[j][1]);
        }
    }
    // epilogue: per-row max / sumexp / top5 in registers (32-lane groups)
#pragma unroll
    for (int j = 0; j < 10; j++) {
        int r = ty * 10 + j;
        int g0 = i0 + tx * 2, g1 = g0 + 1;
        float x0 = (g0 < Vv) ? __fadd_rn(acc[j][0], P.bo[g0]) : -INFINITY;
        float x1 = (g1 < Vv) ? __fadd_rn(acc[j][1], P.bo[g1]) : -INFINITY;
        float mr = fmaxf(x0, x1);
#pragma unroll
        for (int off = 16; off; off >>= 1)
            mr = fmaxf(mr, __shfl_xor(mr, off, 32));
        double s = (double)expf(__fsub_rn(x0, mr)) + (double)expf(__fsub_rn(x1, mr));
#pragma unroll
        for (int off = 16; off; off >>= 1)
            s += __shfl_xor(s, off, 32);
        float tv[5]; int tj[5];
#pragma unroll
        for (int q = 0; q < 5; q++) { tv[q] = -INFINITY; tj[q] = 0x7fffffff; }
        ins5(tv, tj, x0, (g0 < Vv) ? g0 : 0x7fffffff);
        ins5(tv, tj, x1, (g1 < Vv) ? g1 : 0x7fffffff);
#pragma unroll
        for (int lv = 1; lv < 32; lv <<= 1) {
            float pv[5]; int pj[5];
#pragma unroll
            for (int q = 0; q < 5; q++) {
                pv[q] = __shfl_xor(tv[q], lv, 32);
                pj[q] = __shfl_xor(tj[q], lv, 32);
            }
#pragma unroll
            for (int q = 0; q < 5; q++) ins5(tv, tj, pv[q], pj[q]);
        }
        if (tx == 0 && r < N) {
            P.mt_g[(size_t)task * 160 + r] = mr;
            P.st_g[(size_t)task * 160 + r] = s;
#pragma unroll
            for (int q = 0; q < 5; q++) {
                P.t5v[((size_t)task * 160 + r) * 5 + q] = tv[q];
                P.t5j[((size_t)task * 160 + r) * 5 + q] = tj[q];
            }
        }
    }
}

// ---- P5 kernel: per-batch merge + select ----
__global__ __launch_bounds__(512) void p5_k(Params P, int t)
{
    __shared__ float sc[Kb], den[Kb], endd[Kb], len[Kb], mxs[Kb], lgv[Kb];
    __shared__ float mv[256 * 5]; __shared__ int mj[256 * 5];
    __shared__ float mxp[256 * 5];
    __shared__ float rv[512]; __shared__ int rj[512]; __shared__ float rx[512];
    __shared__ double rd[512];
    __shared__ int selj[Kb]; __shared__ float selx[Kb];
    const int tid = threadIdx.x;
    const int b = blockIdx.x;
    const int Kcur = (t == 0) ? 1 : Kb;

    if (tid < Kb) {
        if (t == 0) {
            sc[tid] = 0.f; endd[tid] = 0.f; len[tid] = 0.f; den[tid] = 1.f;
        } else {
            float e0 = P.ended[b * Kb + tid];
            float ln = __fadd_rn(P.lengths[b * Kb + tid], (e0 == 0.f) ? 1.f : 0.f);
            sc[tid]  = P.scores[b * Kb + tid];
            endd[tid] = e0;
            len[tid] = ln;
            den[tid] = (tid < Kb - 1) ? (float)pow((double)ln, (double)0.7f) : 1.f;
        }
    }
    __syncthreads();
    for (int k = 0; k < Kcur; k++) {
        bool active = (t == 0) || (endd[k] == 0.f);
        if (!active) {
            if (tid == 0) { mxs[k] = 0.f; lgv[k] = 0.f; }
            __syncthreads();
            continue;
        }
        int n = b * Kcur + k;
        float m = -INFINITY;
        for (int tile = tid; tile < NTLOG; tile += 512)
            m = fmaxf(m, P.mt_g[(size_t)tile * 160 + n]);
        rv[tid] = m; __syncthreads();
        for (int off = 256; off; off >>= 1) {
            if (tid < off) rv[tid] = fmaxf(rv[tid], rv[tid + off]);
            __syncthreads();
        }
        m = rv[0];
        double s = 0.0;
        for (int tile = tid; tile < NTLOG; tile += 512)
            s += P.st_g[(size_t)tile * 160 + n] *
                 exp((double)(P.mt_g[(size_t)tile * 160 + n] - m));
        __syncthreads();
        rd[tid] = s; __syncthreads();
        for (int off = 256; off; off >>= 1) {
            if (tid < off) rd[tid] += rd[tid + off];
            __syncthreads();
        }
        if (tid == 0) {
            mxs[k] = m;
            float sf = (float)rd[0];
            lgv[k] = (float)log((double)sf);
        }
        __syncthreads();
    }
    // candidate merge: Kcur x 477 x 5 entries
    float tv[5]; int tj[5]; float txx[5];
#pragma unroll
    for (int q = 0; q < 5; q++) { tv[q] = -INFINITY; tj[q] = 0x7fffffff; txx[q] = 0.f; }
    if (tid < 256) {
        int tot = Kcur * NTLOG * 5;
        for (int c = tid; c < tot; c += 256) {
            int k = c / (NTLOG * 5);
            if (t != 0 && endd[k] != 0.f) continue;
            int rm = c - k * NTLOG * 5;
            int tile = rm / 5, q = rm - tile * 5;
            int n = b * Kcur + k;
            int gi = P.t5j[((size_t)tile * 160 + n) * 5 + q];
            if (gi == 0x7fffffff) continue;
            float x = P.t5v[((size_t)tile * 160 + n) * 5 + q];
            float lp  = __fsub_rn(__fsub_rn(x, mxs[k]), lgv[k]);
            float val = __fdiv_rn(__fadd_rn(lp, sc[k]), den[k]);
            ins5p(tv, tj, txx, val, k * Vv + gi, x);
        }
    }
    if (tid == 0 && t != 0) {
        for (int k = 0; k < Kcur; k++)
            if (endd[k] != 0.f) {
                float val = __fdiv_rn(sc[k], den[k]);
                ins5p(tv, tj, txx, val, k * Vv + SEPTOK, 0.f);
            }
    }
    if (tid < 256) {
#pragma unroll
        for (int q = 0; q < 5; q++) {
            mv[tid * 5 + q] = tv[q];
            mj[tid * 5 + q] = tj[q];
            mxp[tid * 5 + q] = txx[q];
        }
    }
    __syncthreads();
    for (int pass = 0; pass < Kb; pass++) {
        if (tid < 256) {
            float bv = -INFINITY; int bj = 0x7fffffff; float bx = 0.f;
#pragma unroll
            for (int q = 0; q < 5; q++) {
                float v = mv[tid * 5 + q]; int j = mj[tid * 5 + q];
                if (betterf(v, j, bv, bj)) { bv = v; bj = j; bx = mxp[tid * 5 + q]; }
            }
            rv[tid] = bv; rj[tid] = bj; rx[tid] = bx;
        }
        __syncthreads();
        for (int off = 128; off; off >>= 1) {
            if (tid < off) {
                float ov = rv[tid + off]; int oj = rj[tid + off];
                if (betterf(ov, oj, rv[tid], rj[tid])) {
                    rv[tid] = ov; rj[tid] = oj; rx[tid] = rx[tid + off];
                }
            }
            __syncthreads();
        }
        if (tid == 0) { selj[pass] = rj[0]; selx[pass] = rx[0]; }
        __syncthreads();
        if (tid < 256) {
#pragma unroll
            for (int q = 0; q < 5; q++)
                if (mj[tid * 5 + q] == selj[pass]) {
                    mv[tid * 5 + q] = -INFINITY;
                    mj[tid * 5 + q] = 0x7fffffff;
                }
        }
        __syncthreads();
    }
    if (tid == 0) {
        for (int q = 0; q < Kb; q++) {
            int jj = selj[q];
            int pk = jj / Vv, vv = jj - pk * Vv;
            float lp;
            if (t == 0 || endd[pk] == 0.f)
                lp = __fsub_rn(__fsub_rn(selx[q], mxs[pk]), lgv[pk]);
            else
                lp = (vv == SEPTOK) ? 0.f : -1e9f;
            float cand = __fadd_rn(lp, sc[pk]);
            P.scores[b * Kb + q]   = cand;
            P.toks_cur[b * Kb + q] = vv;
            P.maps_cur[b * Kb + q] = (t == 0) ? 0 : pk;
            if (t == 0) {
                P.ended[b * Kb + q]   = 0.f;
                P.lengths[b * Kb + q] = 0.f;
            } else {
                P.ended[b * Kb + q]   = (vv == SEPTOK) ? 1.f : endd[q];
                P.lengths[b * Kb + q] = len[q];
            }
            P.toks_all[(size_t)t * Bb * Kb + b * Kb + q] = vv;
            P.maps_all[(size_t)t * Bb * Kb + b * Kb + q] = (t == 0) ? 0 : pk;
        }
    }
}

__global__ void back_k(Params P)
{
    int b = threadIdx.x;
    if (b >= Bb) return;
    int best = 0; float bvv = P.scores[b * Kb];
    for (int k = 1; k < Kb; k++) {
        float v = P.scores[b * Kb + k];
        if (v > bvv) { bvv = v; best = k; }
    }
    int cur = best;
    for (int t = Tt - 1; t >= 0; t--) {
        P.outTok[b * Tt + t] = P.toks_all[t * Bb * Kb + b * Kb + cur];
        cur = P.maps_all[t * Bb * Kb + b * Kb + cur];
    }
}

// ---- one-time srcWa GEMM (r10-proven) ----
template<int RPT, int CPT, bool PMAJ>
__global__ __launch_bounds__(512) void gemmN_k(int P, int I, int xrs, int ldW,
    const float* __restrict__ X, const float* __restrict__ W,
    const float* __restrict__ bias, float* __restrict__ out, int ldO)
{
    constexpr int ROWS = RPT * 16;
    constexpr int COLS = CPT * 32;
    constexpr int XST  = ROWS + 4;
    constexpr int WST  = COLS + 4;
    __shared__ float xs[32][XST];
    __shared__ float wt[32][WST];
    const int tid = threadIdx.x;
    const int ty = tid >> 5, tx = tid & 31;
    const int row0 = blockIdx.y * ROWS;
    const int i0 = blockIdx.x * COLS;

    float acc[RPT][CPT];
#pragma unroll
    for (int j = 0; j < RPT; j++)
#pragma unroll
        for (int u = 0; u < CPT; u++) acc[j][u] = 0.f;

    for (int c0 = 0; c0 < P; c0 += 32) {
        __syncthreads();
        for (int e = tid; e < ROWS * 32; e += 512) {
            int r = e >> 5, p = e & 31;
            xs[p][r] = X[(size_t)(row0 + r) * xrs + c0 + p];
        }
        if (PMAJ) {
            for (int v = tid; v < 32 * (COLS / 4); v += 512) {
                int p  = v / (COLS / 4);
                int i4 = (v % (COLS / 4)) * 4;
                f32x4 a;
                if (i0 + i4 + 3 < I) {
                    a = *(const f32x4*)&W[(size_t)(c0 + p) * ldW + i0 + i4];
                } else {
#pragma unroll
                    for (int u = 0; u < 4; u++) {
                        int g = i0 + i4 + u; if (g >= I) g = I - 1;
                        a[u] = W[(size_t)(c0 + p) * ldW + g];
                    }
                }
                *(f32x4*)&wt[p][i4] = a;
            }
        } else {
            for (int v = tid; v < COLS * 8; v += 512) {
                int c  = v >> 3;
                int p4 = (v & 7) * 4;
                int gi = i0 + c; if (gi >= I) gi = I - 1;
                f32x4 a = *(const f32x4*)&W[(size_t)gi * ldW + c0 + p4];
                wt[p4 + 0][c] = a[0]; wt[p4 + 1][c] = a[1];
                wt[p4 + 2][c] = a[2]; wt[p4 + 3][c] = a[3];
            }
        }
        __syncthreads();
        float part[RPT][CPT];
#pragma unroll
        for (int j = 0; j < RPT; j++)
#pragma unroll
            for (int u = 0; u < CPT; u++) part[j][u] = 0.f;
#pragma unroll
        for (int p = 0; p < 32; p++) {
            float xr[RPT];
#pragma unroll
            for (int j = 0; j < RPT; j += 2) {
                f32x2 xv = *(const f32x2*)&xs[p][ty * RPT + j];
                xr[j] = xv.x; xr[j + 1] = xv.y;
            }
            float wv[CPT];
#pragma unroll
            for (int u = 0; u < CPT; u += 2) {
                f32x2 w2 = *(const f32x2*)&wt[p][tx * CPT + u];
                wv[u] = w2.x; wv[u + 1] = w2.y;
            }
#pragma unroll
            for (int j = 0; j < RPT; j++)
#pragma unroll
                for (int u = 0; u < CPT; u++)
                    part[j][u] = fmaf(xr[j], wv[u], part[j][u]);
        }
#pragma unroll
        for (int j = 0; j < RPT; j++)
#pragma unroll
            for (int u = 0; u < CPT; u++)
                acc[j][u] = __fadd_rn(acc[j][u], part[j][u]);
    }
#pragma unroll
    for (int j = 0; j < RPT; j++) {
        int gr = row0 + ty * RPT + j;
#pragma unroll
        for (int u = 0; u < CPT; u++) {
            int gi = i0 + tx * CPT + u;
            if (gi < I) {
                float v = acc[j][u];
                if (bias) v = __fadd_rn(v, bias[gi]);
                out[(size_t)gr * ldO + gi] = v;
            }
        }
    }
}

// ---------------------------------------------------------------------------
extern "C" void kernel_launch(void* const* d_in, const int* in_sizes, int n_in,
                              void* d_out, int out_size, void* d_ws, size_t ws_size,
                              hipStream_t stream)
{
    Params P;
    P.src  = (const float*)d_in[0];
    P.E    = (const float*)d_in[1];
    P.Wa   = (const float*)d_in[2];
    P.Ua   = (const float*)d_in[3];
    P.va   = (const float*)d_in[4];
    P.W_ih = (const float*)d_in[5];
    P.W_hh = (const float*)d_in[6];
    P.b_ih = (const float*)d_in[7];
    P.b_hh = (const float*)d_in[8];
    P.Wo   = (const float*)d_in[9];
    P.bo   = (const float*)d_in[10];
    P.outTok = (int*)d_out;

    char* w = (char*)d_ws;
    size_t used = 0;
    auto alloc = [&](size_t bytes) -> char* {
        char* p = w + used;
        used += (bytes + 255) & ~(size_t)255;
        return p;
    };
    P.srcWa   = (float*)alloc((size_t)Bb * Ss * Hdim * 4);
    P.hA      = (float*)alloc((size_t)Bb * Kb * Hdim * 4);
    P.hB      = (float*)alloc((size_t)Bb * Kb * Hdim * 4);
    P.hUa     = (float*)alloc((size_t)Bb * Kb * Hdim * 4);
    P.gxE     = (float*)alloc((size_t)Bb * Kb * 2304 * 4);
    P.gx      = (float*)alloc((size_t)Bb * Kb * 2304 * 4);
    P.gh      = (float*)alloc((size_t)Bb * Kb * 2304 * 4);
    P.ctx     = (float*)alloc((size_t)Bb * Kb * Hdim * 4);
    P.mt_g    = (float*)alloc((size_t)NTLOG * 160 * 4);
    P.st_g    = (double*)alloc((size_t)NTLOG * 160 * 8);
    P.t5v     = (float*)alloc((size_t)NTLOG * 160 * 5 * 4);
    P.t5j     = (int*)alloc((size_t)NTLOG * 160 * 5 * 4);
    P.scores  = (float*)alloc(Bb * Kb * 4);
    P.ended   = (float*)alloc(Bb * Kb * 4);
    P.lengths = (float*)alloc(Bb * Kb * 4);
    P.toks_cur = (int*)alloc(Bb * Kb * 4);
    P.maps_cur = (int*)alloc(Bb * Kb * 4);
    P.toks_all = (int*)alloc((size_t)Tt * Bb * Kb * 4);
    P.maps_all = (int*)alloc((size_t)Tt * Bb * Kb * 4);

    // one-time srcWa = src @ Wa
    gemmN_k<8, 2, true><<<dim3(12, 16), 512, 0, stream>>>(
        Hdim, Hdim, Hdim, Hdim, P.src, P.Wa, nullptr, P.srcWa, Hdim);

    for (int t = 0; t < Tt; t++) {
        int N = (t == 0) ? Bb : Bb * Kb;
        p1_k<<<84, 512, 0, stream>>>(P, t, N);
        p2a_k<<<N, 512, 0, stream>>>(P, t, N);
        p2b_k<<<36, 512, 0, stream>>>(P, t, N);
        p2c_k<<<(N * Hdim + 511) / 512, 512, 0, stream>>>(P, t, N);
        p4_k<<<NTLOG, 512, 0, stream>>>(P, t, N);
        p5_k<<<Bb, 512, 0, stream>>>(P, t);
    }
    back_k<<<1, 64, 0, stream>>>(P);
}